// Round 13
// baseline (403.638 us; speedup 1.0000x reference)
//
#include <hip/hip_runtime.h>

// Soft-DTW gradient, batch=64, 256x256, gamma=0.01 — single fused kernel.
// R13 = R12 minus per-body s_barrier: the two waves of a block are now
// decoupled via an LDS producer/consumer flag protocol (4-deep slot ring,
// data -> lgkmcnt(0) -> seq flag; consumer spins, publishes ack for
// back-pressure). The inter-wave dependency has one full body of slack;
// the barrier was discarding it by enforcing lockstep (R8 measured 1.59x
// per-CU throughput for independent waves). Within-wave exchange needs
// only the wave's own lgkmcnt(0) (SIMD lockstep).
// Layout: 64 blocks x 128 threads, block = one element, 2 waves on 2 SIMDs
// of one CU. Lane L owns rows 2L+1, 2L+2. 4-col skew: group g at body
// m = g + L (fwd) / 190 - g - L (bwd). Fwd stores softmin weights (wl,wu);
// bwd pure FMA, E in-place over Wl. Device-scope flag barrier + per-block
// slice reduction (no atomics on out). 3-phase rotating global prefetch.
// ws: Wl/E planes [64][65536] f32, Wu planes [64][65536] f32, counter u32.

#define MM 256
#define NN 256
#define R 2              // rows per virtual lane
#define NB 64            // batch elements / blocks
#define NVL 128          // virtual lanes per element
#define BIGV 1.0e10f
#define K2   144.269504089f     // (1/gamma) * log2(e)
#define GLN2 0.00693147181f     // gamma * ln(2)

#define LDS_VOL(x) (*(volatile int*)&(x))

__device__ __forceinline__ float f4get(const float4& v, int k) {
    switch (k) { case 0: return v.x; case 1: return v.y; case 2: return v.z; default: return v.w; }
}
__device__ __forceinline__ int iclamp(int x, int lo, int hi) {
    return x < lo ? lo : (x > hi ? hi : x);
}
__device__ __forceinline__ float fast_rcp(float x) {
#if __has_builtin(__builtin_amdgcn_rcpf)
    return __builtin_amdgcn_rcpf(x);
#else
    return 1.0f / x;
#endif
}
__device__ __forceinline__ void lds_drain() {
    asm volatile("s_waitcnt lgkmcnt(0)" ::: "memory");
}

__global__ __launch_bounds__(128) void dtw_fused(
    const float* __restrict__ D,
    float* __restrict__ out,          // [256][256]
    float* __restrict__ ws)
{
    const int b = blockIdx.x;                        // batch element
    const int L = threadIdx.x;                       // virtual lane 0..127
    const int w = L >> 6;                            // wave 0/1
    const int t = L & 63;                            // lane in wave
    const float* __restrict__ th = D + (size_t)b * (MM * NN);
    float* __restrict__ Wl = ws + (size_t)b * (MM * NN);               // becomes E plane
    float* __restrict__ Wu = ws + (size_t)NB * (MM * NN) + (size_t)b * (MM * NN);
    unsigned* ctr = (unsigned*)(ws + (size_t)2 * NB * (MM * NN));

    // neighbor-exchange slot rings, depth 4 (ring index = body m & 3).
    // fwd: lane L writes xb[p][L+1], reads xb[p][L]; xb[p][0] = BIGV sentinel.
    //      cross-wave: slot 64 (w0.t63 -> w1.t0), guarded by seqF/ackF.
    // bwd: lane L writes {wb,ub,eb}[p][L], reads [L+1]; [p][NVL] = 0 sentinel.
    //      cross-wave: slot 64 (w1.t0 -> w0.t63), guarded by seqB/ackB.
    __shared__ float4 xb[4][NVL + 1];
    __shared__ float4 wb[4][NVL + 1], ub[4][NVL + 1], eb[4][NVL + 1];
    __shared__ int seqF, ackF, seqB, ackB;

    if (threadIdx.x == 0) {
        #pragma unroll
        for (int p = 0; p < 4; ++p) {
            xb[p][0] = make_float4(BIGV, BIGV, BIGV, BIGV);
            const float4 z = make_float4(0.f, 0.f, 0.f, 0.f);
            wb[p][NVL] = z; ub[p][NVL] = z; eb[p][NVL] = z;
        }
        seqF = -3; ackF = -3; seqB = -3; ackB = -3;
    }
    __syncthreads();

    // ---------------- forward ----------------
    {
        float vprev[R];
        #pragma unroll
        for (int r = 0; r < R; ++r) vprev[r] = BIGV;
        float4 rec = make_float4(BIGV, BIGV, BIGV, BIGV);
        float prevW = BIGV;
        float4 botV4 = make_float4(BIGV, BIGV, BIGV, BIGV);
        float4 thB[3][R];
        #pragma unroll
        for (int p = 0; p < 3; ++p)
            #pragma unroll
            for (int r = 0; r < R; ++r) thB[p][r] = make_float4(0.f, 0.f, 0.f, 0.f);

        auto fwd_body = [&](const int LD, const int CU, const int m) {
            const int g = m - L;
            const int gl = iclamp(g + 2, 0, 63);
            #pragma unroll
            for (int r = 0; r < R; ++r)
                thB[LD][r] = *(const float4*)(th + (2 * L + r) * NN + 4 * gl);
            if (g >= 0 && g <= 63) {
                const float4 topV = rec;             // rows above, cols 4g+1..4g+4
                const float vd0 = (g == 0) ? ((L == 0) ? 0.0f : BIGV) : prevW;
                float wlb[R][4], wub[R][4];
                #pragma unroll
                for (int cc = 0; cc < 4; ++cc) {
                    float vu = f4get(topV, cc);
                    float vd = (cc == 0) ? vd0 : f4get(topV, cc - 1);
                    #pragma unroll
                    for (int r = 0; r < R; ++r) {
                        const float vl = vprev[r];
                        const float mn = fminf(vl, fminf(vd, vu));
                        const float el = exp2f((mn - vl) * K2);
                        const float ed = exp2f((mn - vd) * K2);
                        const float eu = exp2f((mn - vu) * K2);
                        const float ss = el + ed + eu;
                        const float ri = fast_rcp(ss);
                        const float a  = mn - GLN2 * log2f(ss);
                        const float v  = a + f4get(thB[CU][r], cc);
                        wlb[r][cc] = el * ri;
                        wub[r][cc] = eu * ri;
                        vd = vl;
                        vu = v;
                        vprev[r] = v;
                    }
                    if (cc == 0) botV4.x = vprev[R - 1];
                    else if (cc == 1) botV4.y = vprev[R - 1];
                    else if (cc == 2) botV4.z = vprev[R - 1];
                    else botV4.w = vprev[R - 1];
                }
                #pragma unroll
                for (int r = 0; r < R; ++r) {
                    *(float4*)(Wl + (2 * L + r) * NN + 4 * g) =
                        make_float4(wlb[r][0], wlb[r][1], wlb[r][2], wlb[r][3]);
                    *(float4*)(Wu + (2 * L + r) * NN + 4 * g) =
                        make_float4(wub[r][0], wub[r][1], wub[r][2], wub[r][3]);
                }
            }
            // ---- decoupled exchange (no s_barrier) ----
            if (w == 0) { while (LDS_VOL(ackF) < m - 4) {} }   // ring back-pressure
            xb[m & 3][L + 1] = botV4;
            lds_drain();                                        // data visible
            if (w == 0 && t == 63) LDS_VOL(seqF) = m;           // publish
            if (w == 1) { while (LDS_VOL(seqF) < m) {} }        // steady-state: no wait
            asm volatile("" ::: "memory");
            prevW = rec.w;
            rec = xb[m & 3][L];
            if (w == 1 && t == 0) { lds_drain(); LDS_VOL(ackF) = m; }
        };
        for (int k = 0; k < 195; k += 3) {      // m = -2 .. 192
            fwd_body(0, 1, k - 2);
            fwd_body(1, 2, k - 1);
            fwd_body(2, 0, k);
        }
    }

    __threadfence();   // order forward weight-stores before backward loads (same-thread)

    // ---------------- backward (pure FMA, E -> Wl plane in place) ----------------
    {
        float eprev[R], prevWl[R], prevWu[R];
        #pragma unroll
        for (int r = 0; r < R; ++r) { eprev[r] = 0.0f; prevWl[r] = 0.0f; prevWu[r] = 0.0f; }
        float4 WlB[3][R], WuB[3][R];
        #pragma unroll
        for (int p = 0; p < 3; ++p)
            #pragma unroll
            for (int r = 0; r < R; ++r) {
                WlB[p][r] = make_float4(0.f, 0.f, 0.f, 0.f);
                WuB[p][r] = make_float4(0.f, 0.f, 0.f, 0.f);
            }
        float4 recWd = make_float4(0.f, 0.f, 0.f, 0.f);
        float4 recWu = recWd, recE = recWd;
        float pWd = 0.0f, pE = 0.0f;
        float4 topWd4 = recWd, topWu4 = recWd, topE4 = recWd;

        auto bwd_body = [&](const int LD, const int CU, const int m) {
            const int g = 190 - m - L;
            const int gl = iclamp(g - 2, 0, 63);
            #pragma unroll
            for (int r = 0; r < R; ++r) {
                WlB[LD][r] = *(const float4*)(Wl + (2 * L + r) * NN + 4 * gl);
                WuB[LD][r] = *(const float4*)(Wu + (2 * L + r) * NN + 4 * gl);
            }
            if (g >= 0 && g <= 63) {
                const float pWd_ = (g == 63) ? 0.0f : pWd;
                const float pE_  = (g == 63) ? 0.0f : pE;
                float ebuf[R][4];
                #pragma unroll
                for (int cc = 3; cc >= 0; --cc) {
                    float bWd = (cc == 3) ? pWd_ : f4get(recWd, cc + 1);  // wd(i+1, c+1)
                    float bEo = (cc == 3) ? pE_  : f4get(recE,  cc + 1);  // E (i+1, c+1)
                    float bWu = f4get(recWu, cc);                         // wu(i+1, c)
                    float bEn = f4get(recE,  cc);                         // E (i+1, c)
                    #pragma unroll
                    for (int r = R - 1; r >= 0; --r) {
                        const float wlr = (cc == 3) ? prevWl[r] : f4get(WlB[CU][r], cc + 1);
                        float e = wlr * eprev[r] + bWd * bEo + bWu * bEn;
                        if (L == NVL - 1 && r == R - 1 && g == 63 && cc == 3)
                            e = 1.0f;                                   // seed E(M,N)
                        ebuf[r][cc] = e;
                        const float wu_b = (cc == 3) ? prevWu[r] : f4get(WuB[CU][r], cc + 1);
                        bWd = 1.0f - wlr - wu_b;
                        bWu = f4get(WuB[CU][r], cc);
                        bEo = eprev[r];
                        bEn = e;
                        eprev[r] = e;
                    }
                }
                topWd4 = make_float4(
                    1.0f - WlB[CU][0].x - WuB[CU][0].x,
                    1.0f - WlB[CU][0].y - WuB[CU][0].y,
                    1.0f - WlB[CU][0].z - WuB[CU][0].z,
                    1.0f - WlB[CU][0].w - WuB[CU][0].w);
                topWu4 = WuB[CU][0];
                topE4  = make_float4(ebuf[0][0], ebuf[0][1], ebuf[0][2], ebuf[0][3]);
                #pragma unroll
                for (int r = 0; r < R; ++r)                     // E in place of Wl
                    *(float4*)(Wl + (2 * L + r) * NN + 4 * g) =
                        make_float4(ebuf[r][0], ebuf[r][1], ebuf[r][2], ebuf[r][3]);
            }
            // ---- decoupled exchange (no s_barrier); producer = wave 1 ----
            if (w == 1) { while (LDS_VOL(ackB) < m - 4) {} }
            wb[m & 3][L] = topWd4;
            ub[m & 3][L] = topWu4;
            eb[m & 3][L] = topE4;
            lds_drain();
            if (w == 1 && t == 0) LDS_VOL(seqB) = m;
            if (w == 0) { while (LDS_VOL(seqB) < m) {} }
            asm volatile("" ::: "memory");
            pWd = recWd.x; pE = recE.x;
            #pragma unroll
            for (int r = 0; r < R; ++r) {        // own-row W at next group's col0
                prevWl[r] = WlB[CU][r].x;
                prevWu[r] = WuB[CU][r].x;
            }
            recWd = wb[m & 3][L + 1];
            recWu = ub[m & 3][L + 1];
            recE  = eb[m & 3][L + 1];
            if (w == 0 && t == 0) { lds_drain(); LDS_VOL(ackB) = m; }
        };
        for (int k = 0; k < 195; k += 3) {      // m = -2 .. 192
            bwd_body(0, 1, k - 2);
            bwd_body(1, 2, k - 1);
            bwd_body(2, 0, k);
        }
    }

    // ---------------- device-scope barrier (64 blocks) + slice reduction ----------------
    __syncthreads();                               // both waves done, stores drained
    __threadfence();                               // release E stores (L2 writeback)
    if (threadIdx.x == 0)
        __hip_atomic_fetch_add(ctr, 1u, __ATOMIC_ACQ_REL, __HIP_MEMORY_SCOPE_AGENT);
    unsigned cnt;
    do {
        cnt = __hip_atomic_load(ctr, __ATOMIC_ACQUIRE, __HIP_MEMORY_SCOPE_AGENT);
        if (cnt < NB) __builtin_amdgcn_s_sleep(2);
    } while (cnt < NB);
    __builtin_amdgcn_fence(__ATOMIC_ACQUIRE, "agent");   // invalidate caches

    {
        const float* Eall = ws;                    // Wl planes now hold E
        float4 acc[2];
        #pragma unroll
        for (int k2 = 0; k2 < 2; ++k2) acc[k2] = make_float4(0.f, 0.f, 0.f, 0.f);
        for (int p = 0; p < NB; ++p) {
            const float* Ep = Eall + (size_t)p * (MM * NN);
            #pragma unroll
            for (int k2 = 0; k2 < 2; ++k2) {
                const float4 v = *(const float4*)(Ep + 1024 * b + 512 * k2 + 4 * threadIdx.x);
                acc[k2].x += v.x; acc[k2].y += v.y; acc[k2].z += v.z; acc[k2].w += v.w;
            }
        }
        const float inv = 1.0f / (float)NB;
        #pragma unroll
        for (int k2 = 0; k2 < 2; ++k2)
            *(float4*)(out + 1024 * b + 512 * k2 + 4 * threadIdx.x) =
                make_float4(acc[k2].x * inv, acc[k2].y * inv, acc[k2].z * inv, acc[k2].w * inv);
    }
}

extern "C" void kernel_launch(void* const* d_in, const int* in_sizes, int n_in,
                              void* d_out, int out_size, void* d_ws, size_t ws_size,
                              hipStream_t stream) {
    const float* D = (const float*)d_in[0];
    float* out = (float*)d_out;
    float* ws = (float*)d_ws;

    // zero the barrier counter (ws is re-poisoned 0xAA before every launch)
    hipMemsetAsync(ws + (size_t)2 * NB * (MM * NN), 0, sizeof(unsigned), stream);
    dtw_fused<<<dim3(NB), dim3(128), 0, stream>>>(D, out, ws);
}

// Round 14
// 312.493 us; speedup vs baseline: 1.2917x; 1.2917x over previous
//
#include <hip/hip_runtime.h>

// Soft-DTW gradient, batch=64, 256x256, gamma=0.01 — single fused kernel.
// R14 = R12 (best: 273us kernel) + K2-scaled DP domain: V' = V/(gamma*ln2).
// exp2 args become plain differences (no *K2 mul), and since
// K2*gamma*ln2 == 1 exactly, softmin value a' = mn' - log2(ss) (GLN2 mul
// gone); v' = fma(theta, K2, a'). Saves ~4 VALU/cell incl. 2 on the serial
// chain. Weights are scale-invariant -> backward (pure FMA) unchanged.
// Layout: 64 blocks x 128 threads, block = one element, 2 waves on 2 SIMDs
// of one CU. Lane L owns rows 2L+1, 2L+2. 4-col skew: group g at body
// m = g + L (fwd) / 190 - g - L (bwd). Branch-free double-buffered LDS
// neighbor exchange, LDS-only barrier (s_waitcnt lgkmcnt(0); s_barrier).
// Fwd stores softmin weights (wl,wu); bwd pure FMA, E in-place over Wl.
// Device-scope flag barrier + per-block slice reduction (no out atomics).
// ws: Wl/E planes [64][65536] f32, Wu planes [64][65536] f32, counter u32.

#define MM 256
#define NN 256
#define R 2              // rows per virtual lane
#define NB 64            // batch elements / blocks
#define NVL 128          // virtual lanes per element
#define SBIG 1.0e12f     // "infinity" in the scaled domain
#define K2   144.269504089f     // 1/(gamma*ln2) = (1/gamma)*log2(e)

__device__ __forceinline__ float f4get(const float4& v, int k) {
    switch (k) { case 0: return v.x; case 1: return v.y; case 2: return v.z; default: return v.w; }
}
__device__ __forceinline__ int iclamp(int x, int lo, int hi) {
    return x < lo ? lo : (x > hi ? hi : x);
}
__device__ __forceinline__ float fast_rcp(float x) {
#if __has_builtin(__builtin_amdgcn_rcpf)
    return __builtin_amdgcn_rcpf(x);
#else
    return 1.0f / x;
#endif
}
// LDS-visibility-only workgroup barrier: does NOT drain vmcnt, so global
// prefetch loads / weight stores stay in flight across it.
__device__ __forceinline__ void lds_barrier() {
    asm volatile("s_waitcnt lgkmcnt(0)\n\ts_barrier" ::: "memory");
}

__global__ __launch_bounds__(128) void dtw_fused(
    const float* __restrict__ D,
    float* __restrict__ out,          // [256][256]
    float* __restrict__ ws)
{
    const int b = blockIdx.x;                        // batch element
    const int L = threadIdx.x;                       // virtual lane 0..127
    const float* __restrict__ th = D + (size_t)b * (MM * NN);
    float* __restrict__ Wl = ws + (size_t)b * (MM * NN);               // becomes E plane
    float* __restrict__ Wu = ws + (size_t)NB * (MM * NN) + (size_t)b * (MM * NN);
    unsigned* ctr = (unsigned*)(ws + (size_t)2 * NB * (MM * NN));

    // neighbor-exchange slots (double-buffered by macro-step parity).
    // fwd: lane L writes xb[p][L+1], reads xb[p][L]; xb[p][0] = SBIG sentinel.
    // bwd: lane L writes {wb,ub,eb}[p][L], reads [L+1]; [p][NVL] = 0 sentinel.
    __shared__ float4 xb[2][NVL + 1];
    __shared__ float4 wb[2][NVL + 1], ub[2][NVL + 1], eb[2][NVL + 1];

    // ---------------- forward (scaled domain V' = V * K2) ----------------
    {
        float vprev[R];
        #pragma unroll
        for (int r = 0; r < R; ++r) vprev[r] = SBIG;
        float4 rec = make_float4(SBIG, SBIG, SBIG, SBIG);
        float prevW = SBIG;
        float4 botV4 = make_float4(SBIG, SBIG, SBIG, SBIG);
        float4 thB[3][R];
        #pragma unroll
        for (int p = 0; p < 3; ++p)
            #pragma unroll
            for (int r = 0; r < R; ++r) thB[p][r] = make_float4(0.f, 0.f, 0.f, 0.f);

        if (threadIdx.x == 0) {
            xb[0][0] = make_float4(SBIG, SBIG, SBIG, SBIG);
            xb[1][0] = make_float4(SBIG, SBIG, SBIG, SBIG);
        }
        __syncthreads();

        auto fwd_body = [&](const int LD, const int CU, const int m) {
            const int g = m - L;
            const int gl = iclamp(g + 2, 0, 63);
            #pragma unroll
            for (int r = 0; r < R; ++r)
                thB[LD][r] = *(const float4*)(th + (2 * L + r) * NN + 4 * gl);
            if (g >= 0 && g <= 63) {
                const float4 topV = rec;             // rows above, cols 4g+1..4g+4
                const float vd0 = (g == 0) ? ((L == 0) ? 0.0f : SBIG) : prevW;
                float wlb[R][4], wub[R][4];
                #pragma unroll
                for (int cc = 0; cc < 4; ++cc) {
                    float vu = f4get(topV, cc);
                    float vd = (cc == 0) ? vd0 : f4get(topV, cc - 1);
                    #pragma unroll
                    for (int r = 0; r < R; ++r) {
                        const float vl = vprev[r];
                        const float mn = fminf(vl, fminf(vd, vu));
                        const float el = exp2f(mn - vl);
                        const float ed = exp2f(mn - vd);
                        const float eu = exp2f(mn - vu);
                        const float ss = el + ed + eu;
                        const float ri = fast_rcp(ss);
                        const float a  = mn - log2f(ss);            // scaled softmin
                        const float v  = fmaf(f4get(thB[CU][r], cc), K2, a);
                        wlb[r][cc] = el * ri;
                        wub[r][cc] = eu * ri;
                        vd = vl;
                        vu = v;
                        vprev[r] = v;
                    }
                    if (cc == 0) botV4.x = vprev[R - 1];
                    else if (cc == 1) botV4.y = vprev[R - 1];
                    else if (cc == 2) botV4.z = vprev[R - 1];
                    else botV4.w = vprev[R - 1];
                }
                #pragma unroll
                for (int r = 0; r < R; ++r) {
                    *(float4*)(Wl + (2 * L + r) * NN + 4 * g) =
                        make_float4(wlb[r][0], wlb[r][1], wlb[r][2], wlb[r][3]);
                    *(float4*)(Wu + (2 * L + r) * NN + 4 * g) =
                        make_float4(wub[r][0], wub[r][1], wub[r][2], wub[r][3]);
                }
            }
            // ---- branch-free exchange (LDS-only barrier) ----
            xb[m & 1][L + 1] = botV4;
            lds_barrier();
            prevW = rec.w;
            rec = xb[m & 1][L];
        };
        for (int k = 0; k < 195; k += 3) {      // m = -2 .. 192
            fwd_body(0, 1, k - 2);
            fwd_body(1, 2, k - 1);
            fwd_body(2, 0, k);
        }
    }

    __syncthreads();
    __threadfence();   // order forward weight-stores before backward loads

    // ---------------- backward (pure FMA, E -> Wl plane in place) ----------------
    {
        float eprev[R], prevWl[R], prevWu[R];
        #pragma unroll
        for (int r = 0; r < R; ++r) { eprev[r] = 0.0f; prevWl[r] = 0.0f; prevWu[r] = 0.0f; }
        float4 WlB[3][R], WuB[3][R];
        #pragma unroll
        for (int p = 0; p < 3; ++p)
            #pragma unroll
            for (int r = 0; r < R; ++r) {
                WlB[p][r] = make_float4(0.f, 0.f, 0.f, 0.f);
                WuB[p][r] = make_float4(0.f, 0.f, 0.f, 0.f);
            }
        float4 recWd = make_float4(0.f, 0.f, 0.f, 0.f);
        float4 recWu = recWd, recE = recWd;
        float pWd = 0.0f, pE = 0.0f;
        float4 topWd4 = recWd, topWu4 = recWd, topE4 = recWd;

        if (threadIdx.x == 0) {
            const float4 z = make_float4(0.f, 0.f, 0.f, 0.f);
            wb[0][NVL] = z; wb[1][NVL] = z;
            ub[0][NVL] = z; ub[1][NVL] = z;
            eb[0][NVL] = z; eb[1][NVL] = z;
        }
        __syncthreads();

        auto bwd_body = [&](const int LD, const int CU, const int m) {
            const int g = 190 - m - L;
            const int gl = iclamp(g - 2, 0, 63);
            #pragma unroll
            for (int r = 0; r < R; ++r) {
                WlB[LD][r] = *(const float4*)(Wl + (2 * L + r) * NN + 4 * gl);
                WuB[LD][r] = *(const float4*)(Wu + (2 * L + r) * NN + 4 * gl);
            }
            if (g >= 0 && g <= 63) {
                const float pWd_ = (g == 63) ? 0.0f : pWd;
                const float pE_  = (g == 63) ? 0.0f : pE;
                float ebuf[R][4];
                #pragma unroll
                for (int cc = 3; cc >= 0; --cc) {
                    float bWd = (cc == 3) ? pWd_ : f4get(recWd, cc + 1);  // wd(i+1, c+1)
                    float bEo = (cc == 3) ? pE_  : f4get(recE,  cc + 1);  // E (i+1, c+1)
                    float bWu = f4get(recWu, cc);                         // wu(i+1, c)
                    float bEn = f4get(recE,  cc);                         // E (i+1, c)
                    #pragma unroll
                    for (int r = R - 1; r >= 0; --r) {
                        const float wlr = (cc == 3) ? prevWl[r] : f4get(WlB[CU][r], cc + 1);
                        float e = wlr * eprev[r] + bWd * bEo + bWu * bEn;
                        if (L == NVL - 1 && r == R - 1 && g == 63 && cc == 3)
                            e = 1.0f;                                   // seed E(M,N)
                        ebuf[r][cc] = e;
                        const float wu_b = (cc == 3) ? prevWu[r] : f4get(WuB[CU][r], cc + 1);
                        bWd = 1.0f - wlr - wu_b;
                        bWu = f4get(WuB[CU][r], cc);
                        bEo = eprev[r];
                        bEn = e;
                        eprev[r] = e;
                    }
                }
                topWd4 = make_float4(
                    1.0f - WlB[CU][0].x - WuB[CU][0].x,
                    1.0f - WlB[CU][0].y - WuB[CU][0].y,
                    1.0f - WlB[CU][0].z - WuB[CU][0].z,
                    1.0f - WlB[CU][0].w - WuB[CU][0].w);
                topWu4 = WuB[CU][0];
                topE4  = make_float4(ebuf[0][0], ebuf[0][1], ebuf[0][2], ebuf[0][3]);
                #pragma unroll
                for (int r = 0; r < R; ++r)                     // E in place of Wl
                    *(float4*)(Wl + (2 * L + r) * NN + 4 * g) =
                        make_float4(ebuf[r][0], ebuf[r][1], ebuf[r][2], ebuf[r][3]);
            }
            // ---- branch-free exchange (LDS-only barrier) ----
            wb[m & 1][L] = topWd4;
            ub[m & 1][L] = topWu4;
            eb[m & 1][L] = topE4;
            lds_barrier();
            pWd = recWd.x; pE = recE.x;
            #pragma unroll
            for (int r = 0; r < R; ++r) {        // own-row W at next group's col0
                prevWl[r] = WlB[CU][r].x;
                prevWu[r] = WuB[CU][r].x;
            }
            recWd = wb[m & 1][L + 1];
            recWu = ub[m & 1][L + 1];
            recE  = eb[m & 1][L + 1];
        };
        for (int k = 0; k < 195; k += 3) {      // m = -2 .. 192
            bwd_body(0, 1, k - 2);
            bwd_body(1, 2, k - 1);
            bwd_body(2, 0, k);
        }
    }

    // ---------------- device-scope barrier (64 blocks) + slice reduction ----------------
    __syncthreads();                               // both waves done
    __threadfence();                               // release E stores (L2 writeback)
    if (threadIdx.x == 0)
        __hip_atomic_fetch_add(ctr, 1u, __ATOMIC_ACQ_REL, __HIP_MEMORY_SCOPE_AGENT);
    unsigned cnt;
    do {
        cnt = __hip_atomic_load(ctr, __ATOMIC_ACQUIRE, __HIP_MEMORY_SCOPE_AGENT);
        if (cnt < NB) __builtin_amdgcn_s_sleep(2);
    } while (cnt < NB);
    __builtin_amdgcn_fence(__ATOMIC_ACQUIRE, "agent");   // invalidate caches

    {
        const float* Eall = ws;                    // Wl planes now hold E
        float4 acc[2];
        #pragma unroll
        for (int k2 = 0; k2 < 2; ++k2) acc[k2] = make_float4(0.f, 0.f, 0.f, 0.f);
        for (int p = 0; p < NB; ++p) {
            const float* Ep = Eall + (size_t)p * (MM * NN);
            #pragma unroll
            for (int k2 = 0; k2 < 2; ++k2) {
                const float4 v = *(const float4*)(Ep + 1024 * b + 512 * k2 + 4 * threadIdx.x);
                acc[k2].x += v.x; acc[k2].y += v.y; acc[k2].z += v.z; acc[k2].w += v.w;
            }
        }
        const float inv = 1.0f / (float)NB;
        #pragma unroll
        for (int k2 = 0; k2 < 2; ++k2)
            *(float4*)(out + 1024 * b + 512 * k2 + 4 * threadIdx.x) =
                make_float4(acc[k2].x * inv, acc[k2].y * inv, acc[k2].z * inv, acc[k2].w * inv);
    }
}

extern "C" void kernel_launch(void* const* d_in, const int* in_sizes, int n_in,
                              void* d_out, int out_size, void* d_ws, size_t ws_size,
                              hipStream_t stream) {
    const float* D = (const float*)d_in[0];
    float* out = (float*)d_out;
    float* ws = (float*)d_ws;

    // zero the barrier counter (ws is re-poisoned 0xAA before every launch)
    hipMemsetAsync(ws + (size_t)2 * NB * (MM * NN), 0, sizeof(unsigned), stream);
    dtw_fused<<<dim3(NB), dim3(128), 0, stream>>>(D, out, ws);
}